// Round 8
// baseline (1119.462 us; speedup 1.0000x reference)
//
#include <hip/hip_runtime.h>

typedef __bf16 bf16x8_t __attribute__((ext_vector_type(8)));
typedef float f32x4_t __attribute__((ext_vector_type(4)));
typedef float f32x2_t __attribute__((ext_vector_type(2)));

#define NSTEPS 100
// Main loop (per 16-row tile, double-buffered): A:[0,32K)+[32K,64K)  B: +64K
#define APB0 0u
#define APB1 32768u
#define TB   65536u
// Post-loop regions (after SNN/NN partial buffers are dead):
#define POOLA 0u        // pooled CNN frags tile A [0, 51200)
#define POOLB 51200u    // pooled CNN frags tile B [51200, 102400)
#define COMBA 102400u   // comb-input frags tile A [102400, 114688)
#define COMBB 114688u   // comb-input frags tile B [114688, 126976)

static __device__ __forceinline__ unsigned short f2bfu(float v) {
  union { __bf16 h; unsigned short u; } c; c.h = (__bf16)v; return c.u;  // RTNE
}
static __device__ __forceinline__ unsigned int pack2bf(float a, float b) {
  return (unsigned)f2bfu(a) | ((unsigned)f2bfu(b) << 16);
}
union BF8U { unsigned int u[4]; bf16x8_t v; };

// VOP3P packed fp32, in-place. Per-half bitwise-identical to v_mul/v_add_f32.
static __device__ __forceinline__ void pk_mul_ip(f32x2_t &a, f32x2_t b) {
  asm("v_pk_mul_f32 %0, %0, %1" : "+v"(a) : "v"(b));
}
static __device__ __forceinline__ void pk_add_ip(f32x2_t &a, f32x2_t b) {
  asm("v_pk_add_f32 %0, %0, %1" : "+v"(a) : "v"(b));
}

static __device__ __forceinline__ bf16x8_t bfrag_f32(const float* __restrict__ p, float s) {
  BF8U r;
#pragma unroll
  for (int i = 0; i < 4; ++i) r.u[i] = pack2bf(p[2*i]*s, p[2*i+1]*s);
  return r.v;
}

static __device__ __forceinline__ void comb_store(unsigned char* ldsp, unsigned base,
                                                  int k, int row, float v) {
  *(unsigned short*)(ldsp + base +
      (unsigned)((k >> 5)*1024 + (((k >> 3) & 3)*16 + row)*16 + (k & 7)*2)) = f2bfu(v);
}

// 512 threads = 8 waves = 2 waves/SIMD (256-reg budget, the proven no-spill regime).
// v11 = v7 structure x TWO 16-row tiles per block sharing the resident bfr:
// tile B's independent MFMA/LIF/reduce fills tile A's stall slots (ILP not TLP).
// Regs: bfr 64 + 2x(c2 16 + mem2 16 + afr 16) = 160 + ~35 transients <= 256.
__global__ __launch_bounds__(512, 2)
void hybrid_v11(const float* __restrict__ x,
                const float* __restrict__ snn_w1, const float* __restrict__ snn_b1,
                const float* __restrict__ snn_w2, const float* __restrict__ snn_b2,
                const float* __restrict__ nn_w1,  const float* __restrict__ nn_b1,
                const float* __restrict__ nn_w2,  const float* __restrict__ nn_b2,
                const float* __restrict__ conv_w, const float* __restrict__ conv_b,
                const float* __restrict__ fc_w,   const float* __restrict__ fc_b,
                const float* __restrict__ comb_w, const float* __restrict__ comb_b,
                const unsigned short* __restrict__ fcwb, int use_bf,
                float* __restrict__ out)
{
  __shared__ __align__(16) unsigned char lds[131072];
  const int tid  = threadIdx.x;
  const int w    = tid >> 6;        // wave 0..7: K-slice [128w, 128w+128)
  const int l    = tid & 63;
  const int q    = l >> 4;
  const int m    = l & 15;
  const int row0 = blockIdx.x * 32; // 32 rows/block: tile A rows +0..15, tile B +16..31

  const int hi  = w >> 2;
  const int ntr = w & 3;
  const int rn  = ntr*16 + m;       // owned output col 0..63
  const int rA  = hi*4 + q;         // owned row A 0..7 (row B = rA+8) within a tile

  const float b2l = snn_b2[rn];

  // resident snn_w2 B-fragments (shared by BOTH tiles): 4 k-chunks x 4 n-tiles (64 regs)
  bf16x8_t bfr[4][4];
#pragma unroll
  for (int ci = 0; ci < 4; ++ci)
#pragma unroll
    for (int nt = 0; nt < 4; ++nt)
      bfr[ci][nt] = bfrag_f32(snn_w2 + (nt*16 + m)*1024 + (w*4 + ci)*32 + q*8, 1.f);

  // layer-1 LIF state per tile: 32 cells/lane as 16 f32 pairs
  f32x2_t c2A[16], mem2A[16], c2B[16], mem2B[16];
  f32x2_t beta2; beta2.x = 0.95f; beta2.y = 0.95f;
  {
    const int kb = w*128 + q*8;
    // ---- tile A ----
    {
      const float* xr = x + (row0 + m)*105;
      const float f0 = xr[0], f1 = xr[1], f2 = xr[2], f3 = xr[3], f4 = xr[4];
#pragma unroll
      for (int ci = 0; ci < 4; ++ci) {
        const float* wp = snn_w1 + (kb + ci*32)*5;
        float wa[40];
#pragma unroll
        for (int u2 = 0; u2 < 10; ++u2) {
          const float4 t4 = *(const float4*)(wp + u2*4);
          wa[u2*4+0] = t4.x; wa[u2*4+1] = t4.y; wa[u2*4+2] = t4.z; wa[u2*4+3] = t4.w;
        }
        float cc[8];
#pragma unroll
        for (int j = 0; j < 8; ++j)
          cc[j] = f0*wa[j*5] + f1*wa[j*5+1] + f2*wa[j*5+2] + f3*wa[j*5+3] + f4*wa[j*5+4]
                + snn_b1[kb + ci*32 + j];
#pragma unroll
        for (int jj = 0; jj < 4; ++jj) {
          f32x2_t t; t.x = cc[2*jj]; t.y = cc[2*jj+1];
          c2A[ci*4+jj] = t;
          f32x2_t z; z.x = 0.f; z.y = 0.f;
          mem2A[ci*4+jj] = z;
        }
      }
    }
    // ---- tile B ----
    {
      const float* xr = x + (row0 + 16 + m)*105;
      const float f0 = xr[0], f1 = xr[1], f2 = xr[2], f3 = xr[3], f4 = xr[4];
#pragma unroll
      for (int ci = 0; ci < 4; ++ci) {
        const float* wp = snn_w1 + (kb + ci*32)*5;
        float wa[40];
#pragma unroll
        for (int u2 = 0; u2 < 10; ++u2) {
          const float4 t4 = *(const float4*)(wp + u2*4);
          wa[u2*4+0] = t4.x; wa[u2*4+1] = t4.y; wa[u2*4+2] = t4.z; wa[u2*4+3] = t4.w;
        }
        float cc[8];
#pragma unroll
        for (int j = 0; j < 8; ++j)
          cc[j] = f0*wa[j*5] + f1*wa[j*5+1] + f2*wa[j*5+2] + f3*wa[j*5+3] + f4*wa[j*5+4]
                + snn_b1[kb + ci*32 + j];
#pragma unroll
        for (int jj = 0; jj < 4; ++jj) {
          f32x2_t t; t.x = cc[2*jj]; t.y = cc[2*jj+1];
          c2B[ci*4+jj] = t;
          f32x2_t z; z.x = 0.f; z.y = 0.f;
          mem2B[ci*4+jj] = z;
        }
      }
    }
  }

  // spike A-fragments per tile; reset derived from afr words (bit-exact -1.0/-0.0):
  //   lo: (pw<<16)|0x80000000   hi: (pw&0x3F800000)|0x80000000
  BF8U afrA[4], afrB[4];
#pragma unroll
  for (int ci = 0; ci < 4; ++ci)
#pragma unroll
    for (int j = 0; j < 4; ++j) { afrA[ci].u[j] = 0u; afrB[ci].u[j] = 0u; }

  auto lif_stepA = [&]() {
#pragma unroll
    for (int i = 0; i < 16; ++i) {
      const unsigned pw = afrA[i>>2].u[i&3];
      f32x2_t sn;
      sn.x = __uint_as_float((pw << 16) | 0x80000000u);
      sn.y = __uint_as_float((pw & 0x3F800000u) | 0x80000000u);
      pk_mul_ip(mem2A[i], beta2);     // mem = ((0.95*mem) + c) + (-sp)  [exact order]
      pk_add_ip(mem2A[i], c2A[i]);
      pk_add_ip(mem2A[i], sn);
      const unsigned lo  = mem2A[i].x > 1.f ? 0x3F80u     : 0u;
      const unsigned hi2 = mem2A[i].y > 1.f ? 0x3F800000u : 0u;
      afrA[i>>2].u[i&3] = lo | hi2;
    }
  };
  auto lif_stepB = [&]() {
#pragma unroll
    for (int i = 0; i < 16; ++i) {
      const unsigned pw = afrB[i>>2].u[i&3];
      f32x2_t sn;
      sn.x = __uint_as_float((pw << 16) | 0x80000000u);
      sn.y = __uint_as_float((pw & 0x3F800000u) | 0x80000000u);
      pk_mul_ip(mem2B[i], beta2);
      pk_add_ip(mem2B[i], c2B[i]);
      pk_add_ip(mem2B[i], sn);
      const unsigned lo  = mem2B[i].x > 1.f ? 0x3F80u     : 0u;
      const unsigned hi2 = mem2B[i].y > 1.f ? 0x3F800000u : 0u;
      afrB[i>>2].u[i&3] = lo | hi2;
    }
  };
  lif_stepA(); lif_stepB();          // spikes(t=0)

  // layer-2 LIF per tile, packed {rowA, rowB}; counts accumulated negative.
  f32x2_t m2A, s2nA, cntA, m2B, s2nB, cntB, sbias2;
  m2A.x = 0.f; m2A.y = 0.f;  s2nA.x = -0.0f; s2nA.y = -0.0f;  cntA.x = 0.f; cntA.y = 0.f;
  m2B.x = 0.f; m2B.y = 0.f;  s2nB.x = -0.0f; s2nB.y = -0.0f;  cntB.x = 0.f; cntB.y = 0.f;
  sbias2.x = b2l; sbias2.y = b2l;

  // partial layout per buffer (v7-verified): [wave][R%8][col][R/8] f32 (32 KiB)
  const unsigned wbase = (unsigned)(w*4096 + (q&1)*2048 + (q>>1)*4 + m*8);
  const unsigned rbase = (unsigned)(rA*512 + rn*8);
  const f32x4_t z4 = {0.f, 0.f, 0.f, 0.f};

  // exact tree ((0+1)+(2+3))+((4+5)+(6+7)) over 8 b64 reads
  auto tree8 = [&](unsigned off) -> f32x2_t {
    const unsigned char* rp = lds + off + rbase;
    f32x2_t v[8];
#pragma unroll
    for (int s = 0; s < 8; ++s) v[s] = *(const f32x2_t*)(rp + (unsigned)(s*4096));
    pk_add_ip(v[0], v[1]); pk_add_ip(v[2], v[3]);
    pk_add_ip(v[4], v[5]); pk_add_ip(v[6], v[7]);
    pk_add_ip(v[0], v[2]); pk_add_ip(v[4], v[6]);
    pk_add_ip(v[0], v[4]);
    return v[0];
  };
  auto l2up = [&](f32x2_t t, f32x2_t &m2, f32x2_t &s2n, f32x2_t &cnt) {
    pk_add_ip(t, sbias2);
    pk_mul_ip(m2, beta2);
    pk_add_ip(m2, t);
    pk_add_ip(m2, s2n);
    s2n.x = m2.x > 1.f ? -1.0f : -0.0f;
    s2n.y = m2.y > 1.f ? -1.0f : -0.0f;
    pk_add_ip(cnt, s2n);
  };

  // one phase: per tile {MFMA(t) | LIF(t+1) | write(t) | reduce(t-1)}, one barrier
  auto phase = [&](unsigned cur, unsigned prv, bool doRead, bool doLif) {
    {
      f32x4_t acc[4] = {z4, z4, z4, z4};
#pragma unroll
      for (int ci = 0; ci < 4; ++ci)
#pragma unroll
        for (int nt = 0; nt < 4; ++nt)
          acc[nt] = __builtin_amdgcn_mfma_f32_16x16x32_bf16(afrA[ci].v, bfr[ci][nt], acc[nt], 0,0,0);
      if (doLif) lif_stepA();
      unsigned char* wp = lds + cur + wbase;
#pragma unroll
      for (int nt = 0; nt < 4; ++nt)
#pragma unroll
        for (int r = 0; r < 4; ++r)
          *(float*)(wp + (unsigned)(r*512 + nt*128)) = acc[nt][r];
      if (doRead) l2up(tree8(prv), m2A, s2nA, cntA);
    }
    {
      f32x4_t acc[4] = {z4, z4, z4, z4};
#pragma unroll
      for (int ci = 0; ci < 4; ++ci)
#pragma unroll
        for (int nt = 0; nt < 4; ++nt)
          acc[nt] = __builtin_amdgcn_mfma_f32_16x16x32_bf16(afrB[ci].v, bfr[ci][nt], acc[nt], 0,0,0);
      if (doLif) lif_stepB();
      unsigned char* wp = lds + cur + TB + wbase;
#pragma unroll
      for (int nt = 0; nt < 4; ++nt)
#pragma unroll
        for (int r = 0; r < 4; ++r)
          *(float*)(wp + (unsigned)(r*512 + nt*128)) = acc[nt][r];
      if (doRead) l2up(tree8(prv + TB), m2B, s2nB, cntB);
    }
    __syncthreads();
  };

#pragma unroll 1
  for (int tt = 0; tt < NSTEPS; tt += 2) {
    phase(APB0, APB1, tt > 0, true);                 // t = tt
    phase(APB1, APB0, true,  tt + 1 < NSTEPS - 1);   // t = tt+1
  }
  // partials(t=99) sit in APB1 / APB1+TB.

  // epilogue re-derives x row pointers; opaque zero blocks CSE to prologue loads
  int zz = 0; asm volatile("" : "+v"(zz));
  const float* xrA = x + ((row0 + m)*105 + zz);
  const float* xrB = xrA + 16*105;

  // ============ NN branch + final SNN reduce (reads *PB1, writes *PB0) ============
#pragma unroll
  for (int ci = 0; ci < 4; ++ci)
#pragma unroll
    for (int nt = 0; nt < 4; ++nt)
      bfr[ci][nt] = bfrag_f32(nn_w2 + (nt*16 + m)*1024 + (w*4 + ci)*32 + q*8, 1.f);
  {
    // final SNN reduce (t = 99), both tiles
    l2up(tree8(APB1),      m2A, s2nA, cntA);
    l2up(tree8(APB1 + TB), m2B, s2nB, cntB);

    const int kb = w*128 + q*8;
    // ---- tile A hidden + MFMA ----
    {
      const float f0 = xrA[0], f1 = xrA[1], f2 = xrA[2], f3 = xrA[3], f4 = xrA[4];
      BF8U hfr[4];
#pragma unroll
      for (int ci = 0; ci < 4; ++ci) {
        const float* wp = nn_w1 + (kb + ci*32)*5;
        float wa[40];
#pragma unroll
        for (int u2 = 0; u2 < 10; ++u2) {
          const float4 t4 = *(const float4*)(wp + u2*4);
          wa[u2*4+0] = t4.x; wa[u2*4+1] = t4.y; wa[u2*4+2] = t4.z; wa[u2*4+3] = t4.w;
        }
        float hv[8];
#pragma unroll
        for (int j = 0; j < 8; ++j) {
          const float h = f0*wa[j*5] + f1*wa[j*5+1] + f2*wa[j*5+2] + f3*wa[j*5+3] + f4*wa[j*5+4]
                        + nn_b1[kb + ci*32 + j];
          hv[j] = fmaxf(h, 0.f);
        }
#pragma unroll
        for (int jj = 0; jj < 4; ++jj) hfr[ci].u[jj] = pack2bf(hv[2*jj], hv[2*jj+1]);
      }
      f32x4_t acc[4] = {z4, z4, z4, z4};
#pragma unroll
      for (int ci = 0; ci < 4; ++ci)
#pragma unroll
        for (int nt = 0; nt < 4; ++nt)
          acc[nt] = __builtin_amdgcn_mfma_f32_16x16x32_bf16(hfr[ci].v, bfr[ci][nt], acc[nt], 0,0,0);
      unsigned char* wp2 = lds + APB0 + wbase;
#pragma unroll
      for (int nt = 0; nt < 4; ++nt)
#pragma unroll
        for (int r = 0; r < 4; ++r)
          *(float*)(wp2 + (unsigned)(r*512 + nt*128)) = acc[nt][r];
    }
    // ---- tile B hidden + MFMA ----
    {
      const float f0 = xrB[0], f1 = xrB[1], f2 = xrB[2], f3 = xrB[3], f4 = xrB[4];
      BF8U hfr[4];
#pragma unroll
      for (int ci = 0; ci < 4; ++ci) {
        const float* wp = nn_w1 + (kb + ci*32)*5;
        float wa[40];
#pragma unroll
        for (int u2 = 0; u2 < 10; ++u2) {
          const float4 t4 = *(const float4*)(wp + u2*4);
          wa[u2*4+0] = t4.x; wa[u2*4+1] = t4.y; wa[u2*4+2] = t4.z; wa[u2*4+3] = t4.w;
        }
        float hv[8];
#pragma unroll
        for (int j = 0; j < 8; ++j) {
          const float h = f0*wa[j*5] + f1*wa[j*5+1] + f2*wa[j*5+2] + f3*wa[j*5+3] + f4*wa[j*5+4]
                        + nn_b1[kb + ci*32 + j];
          hv[j] = fmaxf(h, 0.f);
        }
#pragma unroll
        for (int jj = 0; jj < 4; ++jj) hfr[ci].u[jj] = pack2bf(hv[2*jj], hv[2*jj+1]);
      }
      f32x4_t acc[4] = {z4, z4, z4, z4};
#pragma unroll
      for (int ci = 0; ci < 4; ++ci)
#pragma unroll
        for (int nt = 0; nt < 4; ++nt)
          acc[nt] = __builtin_amdgcn_mfma_f32_16x16x32_bf16(hfr[ci].v, bfr[ci][nt], acc[nt], 0,0,0);
      unsigned char* wp2 = lds + APB0 + TB + wbase;
#pragma unroll
      for (int nt = 0; nt < 4; ++nt)
#pragma unroll
        for (int r = 0; r < 4; ++r)
          *(float*)(wp2 + (unsigned)(r*512 + nt*128)) = acc[nt][r];
    }
  }
  __syncthreads();
  {
    f32x2_t nA = tree8(APB0);
    f32x2_t nB = tree8(APB0 + TB);
    const float nb = nn_b2[rn];
    f32x2_t nb2; nb2.x = nb; nb2.y = nb;
    pk_add_ip(nA, nb2);
    pk_add_ip(nB, nb2);
    // cnt = -cntneg (integer-valued): x * -0.0078125f == (-x)*0.0078125f bitwise
    comb_store(lds, COMBA, rn,      rA,     cntA.x * -0.0078125f);
    comb_store(lds, COMBA, rn,      rA + 8, cntA.y * -0.0078125f);
    comb_store(lds, COMBA, 64 + rn, rA,     nA.x);
    comb_store(lds, COMBA, 64 + rn, rA + 8, nA.y);
    comb_store(lds, COMBB, rn,      rA,     cntB.x * -0.0078125f);
    comb_store(lds, COMBB, rn,      rA + 8, cntB.y * -0.0078125f);
    comb_store(lds, COMBB, 64 + rn, rA,     nB.x);
    comb_store(lds, COMBB, 64 + rn, rA + 8, nB.y);
  }
  __syncthreads();

  // ======= CNN conv + relu + pairwise maxpool -> pooled bf16 frags, both tiles =======
  {
    const int ch = tid >> 4;          // 0..31  (row = m)
    const float cw0 = conv_w[ch*3+0], cw1 = conv_w[ch*3+1], cw2 = conv_w[ch*3+2];
    const float cbb = conv_b[ch];
    // tile A
    {
      const float* xw = xrA + 5;
      float xm1 = 0.f, x0v = xw[0];
#pragma unroll 1
      for (int p = 0; p < 50; ++p) {
        const float xp1 = xw[2*p + 1];
        const float xp2 = (p < 49) ? xw[2*p + 2] : 0.f;
        const float av = cw0*xm1 + cw1*x0v + cw2*xp1 + cbb;
        const float bv = cw0*x0v + cw1*xp1 + cw2*xp2 + cbb;
        const float pv = fmaxf(fmaxf(av, 0.f), fmaxf(bv, 0.f));
        const int k = ch*50 + p;
        *(unsigned short*)(lds + POOLA +
            (unsigned)((k>>5)*1024 + (((k>>3)&3)*16 + m)*16 + (k&7)*2)) = f2bfu(pv);
        xm1 = xp1; x0v = xp2;
      }
    }
    // tile B
    {
      const float* xw = xrB + 5;
      float xm1 = 0.f, x0v = xw[0];
#pragma unroll 1
      for (int p = 0; p < 50; ++p) {
        const float xp1 = xw[2*p + 1];
        const float xp2 = (p < 49) ? xw[2*p + 2] : 0.f;
        const float av = cw0*xm1 + cw1*x0v + cw2*xp1 + cbb;
        const float bv = cw0*x0v + cw1*xp1 + cw2*xp2 + cbb;
        const float pv = fmaxf(fmaxf(av, 0.f), fmaxf(bv, 0.f));
        const int k = ch*50 + p;
        *(unsigned short*)(lds + POOLB +
            (unsigned)((k>>5)*1024 + (((k>>3)&3)*16 + m)*16 + (k&7)*2)) = f2bfu(pv);
        xm1 = xp1; x0v = xp2;
      }
    }
  }
  __syncthreads();

  // ===== CNN fc: wave w owns n-tiles {2w,2w+1}, both tiles share each weight load =====
  {
    const int c0 = (w*2 + 0)*16 + m;
    const int c1 = (w*2 + 1)*16 + m;
    f32x4_t e0A = z4, o0A = z4, e1A = z4, o1A = z4;
    f32x4_t e0B = z4, o0B = z4, e1B = z4, o1B = z4;
    if (use_bf) {
#pragma unroll 1
      for (int kc = 0; kc < 50; kc += 2) {
        const bf16x8_t a0A = *(const bf16x8_t*)(lds + POOLA + (unsigned)((kc*64 + l)*16));
        const bf16x8_t a1A = *(const bf16x8_t*)(lds + POOLA + (unsigned)(((kc+1)*64 + l)*16));
        const bf16x8_t a0B = *(const bf16x8_t*)(lds + POOLB + (unsigned)((kc*64 + l)*16));
        const bf16x8_t a1B = *(const bf16x8_t*)(lds + POOLB + (unsigned)(((kc+1)*64 + l)*16));
        const bf16x8_t w00 = *(const bf16x8_t*)(fcwb + c0*1600 + kc*32 + q*8);
        const bf16x8_t w01 = *(const bf16x8_t*)(fcwb + c0*1600 + (kc+1)*32 + q*8);
        const bf16x8_t w10 = *(const bf16x8_t*)(fcwb + c1*1600 + kc*32 + q*8);
        const bf16x8_t w11 = *(const bf16x8_t*)(fcwb + c1*1600 + (kc+1)*32 + q*8);
        e0A = __builtin_amdgcn_mfma_f32_16x16x32_bf16(a0A, w00, e0A, 0,0,0);
        o0A = __builtin_amdgcn_mfma_f32_16x16x32_bf16(a1A, w01, o0A, 0,0,0);
        e1A = __builtin_amdgcn_mfma_f32_16x16x32_bf16(a0A, w10, e1A, 0,0,0);
        o1A = __builtin_amdgcn_mfma_f32_16x16x32_bf16(a1A, w11, o1A, 0,0,0);
        e0B = __builtin_amdgcn_mfma_f32_16x16x32_bf16(a0B, w00, e0B, 0,0,0);
        o0B = __builtin_amdgcn_mfma_f32_16x16x32_bf16(a1B, w01, o0B, 0,0,0);
        e1B = __builtin_amdgcn_mfma_f32_16x16x32_bf16(a0B, w10, e1B, 0,0,0);
        o1B = __builtin_amdgcn_mfma_f32_16x16x32_bf16(a1B, w11, o1B, 0,0,0);
      }
    } else {
#pragma unroll 1
      for (int kc = 0; kc < 50; kc += 2) {
        const bf16x8_t a0A = *(const bf16x8_t*)(lds + POOLA + (unsigned)((kc*64 + l)*16));
        const bf16x8_t a1A = *(const bf16x8_t*)(lds + POOLA + (unsigned)(((kc+1)*64 + l)*16));
        const bf16x8_t a0B = *(const bf16x8_t*)(lds + POOLB + (unsigned)((kc*64 + l)*16));
        const bf16x8_t a1B = *(const bf16x8_t*)(lds + POOLB + (unsigned)(((kc+1)*64 + l)*16));
        const bf16x8_t w00 = bfrag_f32(fc_w + c0*1600 + kc*32 + q*8, 1.f);
        const bf16x8_t w01 = bfrag_f32(fc_w + c0*1600 + (kc+1)*32 + q*8, 1.f);
        const bf16x8_t w10 = bfrag_f32(fc_w + c1*1600 + kc*32 + q*8, 1.f);
        const bf16x8_t w11 = bfrag_f32(fc_w + c1*1600 + (kc+1)*32 + q*8, 1.f);
        e0A = __builtin_amdgcn_mfma_f32_16x16x32_bf16(a0A, w00, e0A, 0,0,0);
        o0A = __builtin_amdgcn_mfma_f32_16x16x32_bf16(a1A, w01, o0A, 0,0,0);
        e1A = __builtin_amdgcn_mfma_f32_16x16x32_bf16(a0A, w10, e1A, 0,0,0);
        o1A = __builtin_amdgcn_mfma_f32_16x16x32_bf16(a1A, w11, o1A, 0,0,0);
        e0B = __builtin_amdgcn_mfma_f32_16x16x32_bf16(a0B, w00, e0B, 0,0,0);
        o0B = __builtin_amdgcn_mfma_f32_16x16x32_bf16(a1B, w01, o0B, 0,0,0);
        e1B = __builtin_amdgcn_mfma_f32_16x16x32_bf16(a0B, w10, e1B, 0,0,0);
        o1B = __builtin_amdgcn_mfma_f32_16x16x32_bf16(a1B, w11, o1B, 0,0,0);
      }
    }
    const float fb0 = fc_b[c0], fb1 = fc_b[c1];
#pragma unroll
    for (int r = 0; r < 4; ++r) {
      comb_store(lds, COMBA, 128 + c0, q*4 + r, (e0A[r] + o0A[r]) + fb0);
      comb_store(lds, COMBA, 128 + c1, q*4 + r, (e1A[r] + o1A[r]) + fb1);
      comb_store(lds, COMBB, 128 + c0, q*4 + r, (e0B[r] + o0B[r]) + fb0);
      comb_store(lds, COMBB, 128 + c1, q*4 + r, (e1B[r] + o1B[r]) + fb1);
    }
  }
  __syncthreads();

  // ===== comb matmul: all 8 waves; wave w -> tile (w>>2), n-tile (w&3), K=384 =====
  {
    const int tb = w >> 2;                       // 0=A, 1=B
    const unsigned cb = tb ? COMBB : COMBA;
    const int cn = (w & 3)*16 + m;
    f32x4_t oe = z4, oo = z4;
#pragma unroll
    for (int kc = 0; kc < 12; kc += 2) {
      const bf16x8_t a0 = *(const bf16x8_t*)(lds + cb + (unsigned)((kc*64 + l)*16));
      const bf16x8_t a1 = *(const bf16x8_t*)(lds + cb + (unsigned)(((kc+1)*64 + l)*16));
      const float s0 = (kc    < 2) ? 1.28f : 1.f;   // undo /128 on snn counts -> /100
      const float s1 = (kc+1 < 2) ? 1.28f : 1.f;
      oe = __builtin_amdgcn_mfma_f32_16x16x32_bf16(a0, bfrag_f32(comb_w + cn*384 + kc*32 + q*8, s0), oe, 0,0,0);
      oo = __builtin_amdgcn_mfma_f32_16x16x32_bf16(a1, bfrag_f32(comb_w + cn*384 + (kc+1)*32 + q*8, s1), oo, 0,0,0);
    }
    const float cb2 = comb_b[cn];
#pragma unroll
    for (int r = 0; r < 4; ++r)
      out[(row0 + tb*16 + q*4 + r)*64 + cn] = (oe[r] + oo[r]) + cb2;
  }
}

// fc_w fp32 -> bf16 (runs every call; d_ws is re-poisoned by the harness)
__global__ __launch_bounds__(256)
void fcw_to_bf16(const float* __restrict__ src, unsigned short* __restrict__ dst) {
  const int i = (blockIdx.x * 256 + threadIdx.x) * 4;
  const float4 v = *(const float4*)(src + i);
  ushort4 o;
  o.x = f2bfu(v.x); o.y = f2bfu(v.y); o.z = f2bfu(v.z); o.w = f2bfu(v.w);
  *(ushort4*)(dst + i) = o;
}

extern "C" void kernel_launch(void* const* d_in, const int* in_sizes, int n_in,
                              void* d_out, int out_size, void* d_ws, size_t ws_size,
                              hipStream_t stream) {
  const float* x       = (const float*)d_in[0];
  const float* snn_w1  = (const float*)d_in[1];
  const float* snn_b1  = (const float*)d_in[2];
  const float* snn_w2  = (const float*)d_in[3];
  const float* snn_b2  = (const float*)d_in[4];
  const float* nn_w1   = (const float*)d_in[5];
  const float* nn_b1   = (const float*)d_in[6];
  const float* nn_w2   = (const float*)d_in[7];
  const float* nn_b2   = (const float*)d_in[8];
  const float* conv_w  = (const float*)d_in[9];
  const float* conv_b  = (const float*)d_in[10];
  const float* fc_w    = (const float*)d_in[11];
  const float* fc_b    = (const float*)d_in[12];
  const float* comb_w  = (const float*)d_in[13];
  const float* comb_b  = (const float*)d_in[14];
  float* outp = (float*)d_out;

  const int rows = in_sizes[0] / 105;          // 16384
  const int grid = rows / 32;                  // 512 blocks (32 rows each)

  const size_t fcw_elems = (size_t)in_sizes[11];          // 256*1600 = 409600
  const int use_bf = (ws_size >= fcw_elems * 2) ? 1 : 0;
  unsigned short* fcwb = (unsigned short*)d_ws;
  if (use_bf) {
    fcw_to_bf16<<<dim3((unsigned)(fcw_elems / 1024)), dim3(256), 0, stream>>>(fc_w, fcwb);
  }

  hybrid_v11<<<dim3(grid), dim3(512), 0, stream>>>(
      x, snn_w1, snn_b1, snn_w2, snn_b2,
      nn_w1, nn_b1, nn_w2, nn_b2,
      conv_w, conv_b, fc_w, fc_b, comb_w, comb_b,
      fcwb, use_bf, outp);
}

// Round 9
// 746.715 us; speedup vs baseline: 1.4992x; 1.4992x over previous
//
#include <hip/hip_runtime.h>

typedef __bf16 bf16x8_t __attribute__((ext_vector_type(8)));
typedef float f32x4_t __attribute__((ext_vector_type(4)));
typedef float f32x2_t __attribute__((ext_vector_type(2)));

#define NSTEPS 100
#define PB0 0u          // partials double-buffer: [0,32K) and [32K,64K)
#define PB1 32768u
#define COMBF 51200u    // comb-input bf16 fragments at [51200, 63488) (post-loop only)

static __device__ __forceinline__ unsigned short f2bfu(float v) {
  union { __bf16 h; unsigned short u; } c; c.h = (__bf16)v; return c.u;  // RTNE
}
static __device__ __forceinline__ unsigned int pack2bf(float a, float b) {
  return (unsigned)f2bfu(a) | ((unsigned)f2bfu(b) << 16);
}
union BF8U { unsigned int u[4]; bf16x8_t v; };

// VOP3P packed fp32, in-place. Per-half bitwise-identical to v_mul/v_add_f32.
static __device__ __forceinline__ void pk_mul_ip(f32x2_t &a, f32x2_t b) {
  asm("v_pk_mul_f32 %0, %0, %1" : "+v"(a) : "v"(b));
}
static __device__ __forceinline__ void pk_add_ip(f32x2_t &a, f32x2_t b) {
  asm("v_pk_add_f32 %0, %0, %1" : "+v"(a) : "v"(b));
}

static __device__ __forceinline__ bf16x8_t bfrag_f32(const float* __restrict__ p, float s) {
  BF8U r;
#pragma unroll
  for (int i = 0; i < 4; ++i) r.u[i] = pack2bf(p[2*i]*s, p[2*i+1]*s);
  return r.v;
}

static __device__ __forceinline__ void comb_store(unsigned char* ldsp, int k, int row, float v) {
  *(unsigned short*)(ldsp + COMBF +
      (unsigned)((k >> 5)*1024 + (((k >> 3) & 3)*16 + row)*16 + (k & 7)*2)) = f2bfu(v);
}

// 512 threads = 8 waves = 2 waves/SIMD (256-reg budget; the proven no-spill regime).
// v12 = v5 (660us best) + two scheduling fixes, arithmetic bit-identical:
//  (a) lif between MFMA and writes: own-wave lif covers the MFMA-tail->accvgpr wait
//      (both waves lockstep -> this stall was fully exposed in v5's order)
//  (b) ds_write2_b32 x8 instead of 16x ds_write_b32 (pairs at +512B, dword offsets fit)
__global__ __launch_bounds__(512, 2)
void hybrid_v12(const float* __restrict__ x,
                const float* __restrict__ snn_w1, const float* __restrict__ snn_b1,
                const float* __restrict__ snn_w2, const float* __restrict__ snn_b2,
                const float* __restrict__ nn_w1,  const float* __restrict__ nn_b1,
                const float* __restrict__ nn_w2,  const float* __restrict__ nn_b2,
                const float* __restrict__ conv_w, const float* __restrict__ conv_b,
                const float* __restrict__ fc_w,   const float* __restrict__ fc_b,
                const float* __restrict__ comb_w, const float* __restrict__ comb_b,
                const unsigned short* __restrict__ fcwb, int use_bf,
                float* __restrict__ out)
{
  __shared__ __align__(16) unsigned char lds[65536];
  const int tid  = threadIdx.x;
  const int w    = tid >> 6;        // wave 0..7: K-slice [128w, 128w+128)
  const int l    = tid & 63;
  const int q    = l >> 4;
  const int m    = l & 15;
  const int row0 = blockIdx.x * 16;

  const int hi  = w >> 2;
  const int ntr = w & 3;
  const int rn  = ntr*16 + m;       // owned output col 0..63
  const int rA  = hi*4 + q;         // owned row A 0..7 (row B = rA+8)

  const float* xr = x + (row0 + m)*105;
  const float f0 = xr[0], f1 = xr[1], f2 = xr[2], f3 = xr[3], f4 = xr[4];
  const float b2l = snn_b2[rn];

  // resident snn_w2 B-fragments: 4 k-chunks x 4 n-tiles (64 regs, AGPR-eligible)
  bf16x8_t bfr[4][4];
#pragma unroll
  for (int ci = 0; ci < 4; ++ci)
#pragma unroll
    for (int nt = 0; nt < 4; ++nt)
      bfr[ci][nt] = bfrag_f32(snn_w2 + (nt*16 + m)*1024 + (w*4 + ci)*32 + q*8, 1.f);

  // layer-1 LIF state: lane's 32 A-fragment cells, packed as 16 f32 pairs.
  // spneg2 holds spikes as {-1.0f or -0.0f}: x + (-sp) is bit-identical to x - sp.
  f32x2_t c2[16], mem2[16], spneg2[16];
  f32x2_t beta2; beta2.x = 0.95f; beta2.y = 0.95f;
  {
    const int kb = w*128 + q*8;
#pragma unroll
    for (int ci = 0; ci < 4; ++ci) {
      const float* wp = snn_w1 + (kb + ci*32)*5;
      float wa[40];
#pragma unroll
      for (int u2 = 0; u2 < 10; ++u2) {
        const float4 t4 = *(const float4*)(wp + u2*4);
        wa[u2*4+0] = t4.x; wa[u2*4+1] = t4.y; wa[u2*4+2] = t4.z; wa[u2*4+3] = t4.w;
      }
      float cc[8];
#pragma unroll
      for (int j = 0; j < 8; ++j)
        cc[j] = f0*wa[j*5] + f1*wa[j*5+1] + f2*wa[j*5+2] + f3*wa[j*5+3] + f4*wa[j*5+4]
              + snn_b1[kb + ci*32 + j];
#pragma unroll
      for (int jj = 0; jj < 4; ++jj) {
        f32x2_t t; t.x = cc[2*jj]; t.y = cc[2*jj+1];
        c2[ci*4+jj] = t;
        f32x2_t z; z.x = 0.f; z.y = 0.f;
        mem2[ci*4+jj] = z;
        f32x2_t nz; nz.x = -0.0f; nz.y = -0.0f;
        spneg2[ci*4+jj] = nz;
      }
    }
  }

  BF8U afr[4];
  // mem = ((0.95*mem) + c) + (-sp)  [exact np order]; emit spikes for this step.
  // afr word via perm(sn.y, sn.x) & 0x3F803F80: {-1.0,-0.0} -> packed bf16 {1.0, 0.0}.
  auto lif_step = [&]() {
#pragma unroll
    for (int i = 0; i < 16; ++i) {
      pk_mul_ip(mem2[i], beta2);
      pk_add_ip(mem2[i], c2[i]);
      pk_add_ip(mem2[i], spneg2[i]);
      f32x2_t sn;
      sn.x = mem2[i].x > 1.f ? -1.0f : -0.0f;
      sn.y = mem2[i].y > 1.f ? -1.0f : -0.0f;
      spneg2[i] = sn;
      afr[i>>2].u[i&3] =
          __builtin_amdgcn_perm(__float_as_uint(sn.y), __float_as_uint(sn.x), 0x07060302u)
          & 0x3F803F80u;
    }
  };
  lif_step();                        // spikes(t=0)

  // layer-2 LIF state, packed {rowA, rowB}; counts accumulated negative.
  f32x2_t m2;     m2.x = 0.f;      m2.y = 0.f;
  f32x2_t s2neg;  s2neg.x = -0.0f; s2neg.y = -0.0f;
  f32x2_t cntneg; cntneg.x = 0.f;  cntneg.y = 0.f;
  f32x2_t sbias2; sbias2.x = b2l;  sbias2.y = b2l;

  // partial layout per buffer: [wave][R%8][col][R/8] f32 (32 KiB each)
  const unsigned wbase = (unsigned)(w*4096 + (q&1)*2048 + (q>>1)*4 + m*8);
  const unsigned rbase = (unsigned)(rA*512 + rn*8);
  const f32x4_t z4 = {0.f, 0.f, 0.f, 0.f};

  // write-addr regs for ds_write2 (byte addresses into LDS address space)
  const unsigned a0_pb0 = (unsigned)(uintptr_t)(lds + PB0 + wbase);
  const unsigned a1_pb0 = a0_pb0 + 1024u;
  const unsigned a0_pb1 = (unsigned)(uintptr_t)(lds + PB1 + wbase);
  const unsigned a1_pb1 = a0_pb1 + 1024u;

  auto reduce_lif2 = [&](unsigned prv) {
    const unsigned char* rp = lds + prv + rbase;
    f32x2_t v[8];
#pragma unroll
    for (int s = 0; s < 8; ++s) v[s] = *(const f32x2_t*)(rp + (unsigned)(s*4096));
    pk_add_ip(v[0], v[1]); pk_add_ip(v[2], v[3]);
    pk_add_ip(v[4], v[5]); pk_add_ip(v[6], v[7]);
    pk_add_ip(v[0], v[2]); pk_add_ip(v[4], v[6]);
    pk_add_ip(v[0], v[4]);
    pk_add_ip(v[0], sbias2);
    pk_mul_ip(m2, beta2);
    pk_add_ip(m2, v[0]);
    pk_add_ip(m2, s2neg);
    s2neg.x = m2.x > 1.f ? -1.0f : -0.0f;
    s2neg.y = m2.y > 1.f ? -1.0f : -0.0f;
    pk_add_ip(cntneg, s2neg);
  };

  // phase: MFMA(t) | lif(t+1) [covers MFMA tail] | write2(t) | reduce(t-1) | barrier
  auto phase = [&](unsigned wa0, unsigned wa1, unsigned prv, bool doRead, bool doLif) {
    f32x4_t acc[4] = {z4, z4, z4, z4};
#pragma unroll
    for (int ci = 0; ci < 4; ++ci)
#pragma unroll
      for (int nt = 0; nt < 4; ++nt)
        acc[nt] = __builtin_amdgcn_mfma_f32_16x16x32_bf16(afr[ci].v, bfr[ci][nt], acc[nt], 0,0,0);
    if (doLif) lif_step();           // independent VALU; fills the MFMA-completion wait
    // 8x ds_write2_b32: (nt, r=0/1) at wa0 + nt*128(B) {+0,+512}; (r=2/3) at wa1
    asm volatile(
      "ds_write2_b32 %0, %2, %3 offset0:0  offset1:128\n\t"
      "ds_write2_b32 %1, %4, %5 offset0:0  offset1:128\n\t"
      "ds_write2_b32 %0, %6, %7 offset0:32 offset1:160\n\t"
      "ds_write2_b32 %1, %8, %9 offset0:32 offset1:160"
      :: "v"(wa0), "v"(wa1),
         "v"(acc[0][0]), "v"(acc[0][1]), "v"(acc[0][2]), "v"(acc[0][3]),
         "v"(acc[1][0]), "v"(acc[1][1]), "v"(acc[1][2]), "v"(acc[1][3])
      : "memory");
    asm volatile(
      "ds_write2_b32 %0, %2, %3 offset0:64 offset1:192\n\t"
      "ds_write2_b32 %1, %4, %5 offset0:64 offset1:192\n\t"
      "ds_write2_b32 %0, %6, %7 offset0:96 offset1:224\n\t"
      "ds_write2_b32 %1, %8, %9 offset0:96 offset1:224"
      :: "v"(wa0), "v"(wa1),
         "v"(acc[2][0]), "v"(acc[2][1]), "v"(acc[2][2]), "v"(acc[2][3]),
         "v"(acc[3][0]), "v"(acc[3][1]), "v"(acc[3][2]), "v"(acc[3][3])
      : "memory");
    if (doRead) reduce_lif2(prv);    // reads+tree cover the write drain
    __syncthreads();
  };

#pragma unroll 1
  for (int tt = 0; tt < NSTEPS; tt += 2) {
    phase(a0_pb0, a1_pb0, PB1, tt > 0, true);                 // t = tt
    phase(a0_pb1, a1_pb1, PB0, true,  tt + 1 < NSTEPS - 1);   // t = tt+1
  }
  // partials(99) sit in PB1; reduced below, folded into the NN phase.

  // ============ NN branch + final SNN reduce (reads PB1, writes PB0) ============
#pragma unroll
  for (int ci = 0; ci < 4; ++ci)
#pragma unroll
    for (int nt = 0; nt < 4; ++nt)
      bfr[ci][nt] = bfrag_f32(nn_w2 + (nt*16 + m)*1024 + (w*4 + ci)*32 + q*8, 1.f);
  {
    // final SNN reduce (t = 99)
    reduce_lif2(PB1);

    // NN hidden + MFMA
    BF8U hfr[4];
    const int kb = w*128 + q*8;
#pragma unroll
    for (int ci = 0; ci < 4; ++ci) {
      const float* wp = nn_w1 + (kb + ci*32)*5;
      float wa[40];
#pragma unroll
      for (int u2 = 0; u2 < 10; ++u2) {
        const float4 t4 = *(const float4*)(wp + u2*4);
        wa[u2*4+0] = t4.x; wa[u2*4+1] = t4.y; wa[u2*4+2] = t4.z; wa[u2*4+3] = t4.w;
      }
      float hv[8];
#pragma unroll
      for (int j = 0; j < 8; ++j) {
        const float h = f0*wa[j*5] + f1*wa[j*5+1] + f2*wa[j*5+2] + f3*wa[j*5+3] + f4*wa[j*5+4]
                      + nn_b1[kb + ci*32 + j];
        hv[j] = fmaxf(h, 0.f);
      }
#pragma unroll
      for (int jj = 0; jj < 4; ++jj) hfr[ci].u[jj] = pack2bf(hv[2*jj], hv[2*jj+1]);
    }
    f32x4_t acc[4] = {z4, z4, z4, z4};
#pragma unroll
    for (int ci = 0; ci < 4; ++ci)
#pragma unroll
      for (int nt = 0; nt < 4; ++nt)
        acc[nt] = __builtin_amdgcn_mfma_f32_16x16x32_bf16(hfr[ci].v, bfr[ci][nt], acc[nt], 0,0,0);
#pragma unroll
    for (int nt = 0; nt < 4; ++nt)
#pragma unroll
      for (int r = 0; r < 4; ++r)
        *(float*)(lds + PB0 + wbase + (unsigned)(r*512 + nt*128)) = acc[nt][r];
  }
  __syncthreads();
  {
    f32x2_t v[8];
    const unsigned char* rp = lds + PB0 + rbase;
#pragma unroll
    for (int s = 0; s < 8; ++s) v[s] = *(const f32x2_t*)(rp + (unsigned)(s*4096));
    pk_add_ip(v[0], v[1]); pk_add_ip(v[2], v[3]);
    pk_add_ip(v[4], v[5]); pk_add_ip(v[6], v[7]);
    pk_add_ip(v[0], v[2]); pk_add_ip(v[4], v[6]);
    pk_add_ip(v[0], v[4]);
    const float nb = nn_b2[rn];
    f32x2_t nb2; nb2.x = nb; nb2.y = nb;
    pk_add_ip(v[0], nb2);
    // cnt = -cntneg (integer-valued): x * -0.0078125f == (-x)*0.0078125f bitwise
    comb_store(lds, rn,      rA,     cntneg.x * -0.0078125f);
    comb_store(lds, rn,      rA + 8, cntneg.y * -0.0078125f);
    comb_store(lds, 64 + rn, rA,     v[0].x);
    comb_store(lds, 64 + rn, rA + 8, v[0].y);
  }
  __syncthreads();

  // ======= CNN conv + relu + pairwise maxpool -> pooled bf16 frags [0,51200) =======
  {
    const int ch = tid >> 4;          // 0..31  (row = m)
    const float cw0 = conv_w[ch*3+0], cw1 = conv_w[ch*3+1], cw2 = conv_w[ch*3+2];
    const float cbb = conv_b[ch];
    const float* xw = xr + 5;
    float xm1 = 0.f, x0v = xw[0];
#pragma unroll 1
    for (int p = 0; p < 50; ++p) {
      const float xp1 = xw[2*p + 1];
      const float xp2 = (p < 49) ? xw[2*p + 2] : 0.f;
      const float av = cw0*xm1 + cw1*x0v + cw2*xp1 + cbb;
      const float bv = cw0*x0v + cw1*xp1 + cw2*xp2 + cbb;
      const float pv = fmaxf(fmaxf(av, 0.f), fmaxf(bv, 0.f));
      const int k = ch*50 + p;
      *(unsigned short*)(lds + (unsigned)((k>>5)*1024 + (((k>>3)&3)*16 + m)*16 + (k&7)*2)) = f2bfu(pv);
      xm1 = xp1; x0v = xp2;
    }
  }
  __syncthreads();

  // ================= CNN fc: wave w owns n-tiles {2w, 2w+1}, full K=1600 =================
  {
    const int c0 = (w*2 + 0)*16 + m;
    const int c1 = (w*2 + 1)*16 + m;
    f32x4_t e0 = z4, o0 = z4, e1 = z4, o1 = z4;
    if (use_bf) {
#pragma unroll 2
      for (int kc = 0; kc < 50; kc += 2) {
        const bf16x8_t a0 = *(const bf16x8_t*)(lds + (unsigned)((kc*64 + l)*16));
        const bf16x8_t a1 = *(const bf16x8_t*)(lds + (unsigned)(((kc+1)*64 + l)*16));
        e0 = __builtin_amdgcn_mfma_f32_16x16x32_bf16(a0, *(const bf16x8_t*)(fcwb + c0*1600 + kc*32 + q*8), e0, 0,0,0);
        o0 = __builtin_amdgcn_mfma_f32_16x16x32_bf16(a1, *(const bf16x8_t*)(fcwb + c0*1600 + (kc+1)*32 + q*8), o0, 0,0,0);
        e1 = __builtin_amdgcn_mfma_f32_16x16x32_bf16(a0, *(const bf16x8_t*)(fcwb + c1*1600 + kc*32 + q*8), e1, 0,0,0);
        o1 = __builtin_amdgcn_mfma_f32_16x16x32_bf16(a1, *(const bf16x8_t*)(fcwb + c1*1600 + (kc+1)*32 + q*8), o1, 0,0,0);
      }
    } else {
#pragma unroll 2
      for (int kc = 0; kc < 50; kc += 2) {
        const bf16x8_t a0 = *(const bf16x8_t*)(lds + (unsigned)((kc*64 + l)*16));
        const bf16x8_t a1 = *(const bf16x8_t*)(lds + (unsigned)(((kc+1)*64 + l)*16));
        e0 = __builtin_amdgcn_mfma_f32_16x16x32_bf16(a0, bfrag_f32(fc_w + c0*1600 + kc*32 + q*8, 1.f), e0, 0,0,0);
        o0 = __builtin_amdgcn_mfma_f32_16x16x32_bf16(a1, bfrag_f32(fc_w + c0*1600 + (kc+1)*32 + q*8, 1.f), o0, 0,0,0);
        e1 = __builtin_amdgcn_mfma_f32_16x16x32_bf16(a0, bfrag_f32(fc_w + c1*1600 + kc*32 + q*8, 1.f), e1, 0,0,0);
        o1 = __builtin_amdgcn_mfma_f32_16x16x32_bf16(a1, bfrag_f32(fc_w + c1*1600 + (kc+1)*32 + q*8, 1.f), o1, 0,0,0);
      }
    }
    const float fb0 = fc_b[c0], fb1 = fc_b[c1];
#pragma unroll
    for (int r = 0; r < 4; ++r) {
      comb_store(lds, 128 + c0, q*4 + r, (e0[r] + o0[r]) + fb0);
      comb_store(lds, 128 + c1, q*4 + r, (e1[r] + o1[r]) + fb1);
    }
  }
  __syncthreads();

  // ================= comb matmul: waves 0..3, wave w owns n-tile w, full K=384 =================
  if (w < 4) {
    const int cn = w*16 + m;
    f32x4_t oe = z4, oo = z4;
#pragma unroll
    for (int kc = 0; kc < 12; kc += 2) {
      const bf16x8_t a0 = *(const bf16x8_t*)(lds + COMBF + (unsigned)((kc*64 + l)*16));
      const bf16x8_t a1 = *(const bf16x8_t*)(lds + COMBF + (unsigned)(((kc+1)*64 + l)*16));
      const float s0 = (kc    < 2) ? 1.28f : 1.f;   // undo /128 on snn counts -> /100
      const float s1 = (kc+1 < 2) ? 1.28f : 1.f;
      oe = __builtin_amdgcn_mfma_f32_16x16x32_bf16(a0, bfrag_f32(comb_w + cn*384 + kc*32 + q*8, s0), oe, 0,0,0);
      oo = __builtin_amdgcn_mfma_f32_16x16x32_bf16(a1, bfrag_f32(comb_w + cn*384 + (kc+1)*32 + q*8, s1), oo, 0,0,0);
    }
    const float cb2 = comb_b[cn];
#pragma unroll
    for (int r = 0; r < 4; ++r)
      out[(row0 + q*4 + r)*64 + cn] = (oe[r] + oo[r]) + cb2;
  }
}

// fc_w fp32 -> bf16 (runs every call; d_ws is re-poisoned by the harness)
__global__ __launch_bounds__(256)
void fcw_to_bf16(const float* __restrict__ src, unsigned short* __restrict__ dst) {
  const int i = (blockIdx.x * 256 + threadIdx.x) * 4;
  const float4 v = *(const float4*)(src + i);
  ushort4 o;
  o.x = f2bfu(v.x); o.y = f2bfu(v.y); o.z = f2bfu(v.z); o.w = f2bfu(v.w);
  *(ushort4*)(dst + i) = o;
}

extern "C" void kernel_launch(void* const* d_in, const int* in_sizes, int n_in,
                              void* d_out, int out_size, void* d_ws, size_t ws_size,
                              hipStream_t stream) {
  const float* x       = (const float*)d_in[0];
  const float* snn_w1  = (const float*)d_in[1];
  const float* snn_b1  = (const float*)d_in[2];
  const float* snn_w2  = (const float*)d_in[3];
  const float* snn_b2  = (const float*)d_in[4];
  const float* nn_w1   = (const float*)d_in[5];
  const float* nn_b1   = (const float*)d_in[6];
  const float* nn_w2   = (const float*)d_in[7];
  const float* nn_b2   = (const float*)d_in[8];
  const float* conv_w  = (const float*)d_in[9];
  const float* conv_b  = (const float*)d_in[10];
  const float* fc_w    = (const float*)d_in[11];
  const float* fc_b    = (const float*)d_in[12];
  const float* comb_w  = (const float*)d_in[13];
  const float* comb_b  = (const float*)d_in[14];
  float* outp = (float*)d_out;

  const int rows = in_sizes[0] / 105;          // 16384
  const int grid = rows / 16;                  // 1024

  const size_t fcw_elems = (size_t)in_sizes[11];          // 256*1600 = 409600
  const int use_bf = (ws_size >= fcw_elems * 2) ? 1 : 0;
  unsigned short* fcwb = (unsigned short*)d_ws;
  if (use_bf) {
    fcw_to_bf16<<<dim3((unsigned)(fcw_elems / 1024)), dim3(256), 0, stream>>>(fc_w, fcwb);
  }

  hybrid_v12<<<dim3(grid), dim3(512), 0, stream>>>(
      x, snn_w1, snn_b1, snn_w2, snn_b2,
      nn_w1, nn_b1, nn_w2, nn_b2,
      conv_w, conv_b, fc_w, fc_b, comb_w, comb_b,
      fcwb, use_bf, outp);
}

// Round 11
// 685.148 us; speedup vs baseline: 1.6339x; 1.0899x over previous
//
#include <hip/hip_runtime.h>

typedef __bf16 bf16x8_t __attribute__((ext_vector_type(8)));
typedef float f32x4_t __attribute__((ext_vector_type(4)));
typedef float f32x2_t __attribute__((ext_vector_type(2)));

#define NSTEPS 100
#define PB0 0u          // partials double-buffer: [0,32K) and [32K,64K)
#define PB1 32768u
#define COMBF 51200u    // comb-input bf16 fragments at [51200, 63488) (post-loop only)

static __device__ __forceinline__ unsigned short f2bfu(float v) {
  union { __bf16 h; unsigned short u; } c; c.h = (__bf16)v; return c.u;  // RTNE
}
static __device__ __forceinline__ unsigned int pack2bf(float a, float b) {
  return (unsigned)f2bfu(a) | ((unsigned)f2bfu(b) << 16);
}
union BF8U { unsigned int u[4]; bf16x8_t v; };

// VOP3P packed fp32 (gfx90a+, present on gfx950): elementwise IEEE mul/add on a
// VGPR pair. Per-half bitwise-identical to v_mul_f32/v_add_f32 -> exactness kept.
static __device__ __forceinline__ f32x2_t pk_mul(f32x2_t a, f32x2_t b) {
  f32x2_t d; asm("v_pk_mul_f32 %0, %1, %2" : "=v"(d) : "v"(a), "v"(b)); return d;
}
static __device__ __forceinline__ f32x2_t pk_add(f32x2_t a, f32x2_t b) {
  f32x2_t d; asm("v_pk_add_f32 %0, %1, %2" : "=v"(d) : "v"(a), "v"(b)); return d;
}

static __device__ __forceinline__ bf16x8_t bfrag_f32(const float* __restrict__ p, float s) {
  BF8U r;
#pragma unroll
  for (int i = 0; i < 4; ++i) r.u[i] = pack2bf(p[2*i]*s, p[2*i+1]*s);
  return r.v;
}

static __device__ __forceinline__ void comb_store(unsigned char* ldsp, int k, int row, float v) {
  *(unsigned short*)(ldsp + COMBF +
      (unsigned)((k >> 5)*1024 + (((k >> 3) & 3)*16 + row)*16 + (k & 7)*2)) = f2bfu(v);
}

// 512 threads = 8 waves = 2 waves/SIMD -> 256-reg unified budget.
// ~225 regs used (mem2/c2/spneg2 pairs + 64 bfr + afr): 2 waves/SIMD, no spill.
// Phase order (reads-first / writes-early / compute-late) is the session's verified
// optimum: reads(t-1) hide under MFMA+writes+lif; DS write drain hides under lif.
// 8 structural variants (superstep, 16-wave TLP x3, 2-tile ILP, reorders) all
// regressed or were neutral vs this arrangement.
__global__ __launch_bounds__(512, 2)
void hybrid_v13(const float* __restrict__ x,
                const float* __restrict__ snn_w1, const float* __restrict__ snn_b1,
                const float* __restrict__ snn_w2, const float* __restrict__ snn_b2,
                const float* __restrict__ nn_w1,  const float* __restrict__ nn_b1,
                const float* __restrict__ nn_w2,  const float* __restrict__ nn_b2,
                const float* __restrict__ conv_w, const float* __restrict__ conv_b,
                const float* __restrict__ fc_w,   const float* __restrict__ fc_b,
                const float* __restrict__ comb_w, const float* __restrict__ comb_b,
                const unsigned short* __restrict__ fcwb, int use_bf,
                float* __restrict__ out)
{
  __shared__ __align__(16) unsigned char lds[65536];
  const int tid  = threadIdx.x;
  const int w    = tid >> 6;        // wave 0..7: K-slice [128w, 128w+128)
  const int l    = tid & 63;
  const int q    = l >> 4;
  const int m    = l & 15;
  const int row0 = blockIdx.x * 16;

  const int hi  = w >> 2;
  const int ntr = w & 3;
  const int rn  = ntr*16 + m;       // owned output col 0..63
  const int rA  = hi*4 + q;         // owned row A 0..7 (row B = rA+8)

  const float* xr = x + (row0 + m)*105;
  const float f0 = xr[0], f1 = xr[1], f2 = xr[2], f3 = xr[3], f4 = xr[4];
  const float b2l = snn_b2[rn];

  // resident snn_w2 B-fragments: 4 k-chunks x 4 n-tiles (64 regs, AGPR-eligible)
  bf16x8_t bfr[4][4];
#pragma unroll
  for (int ci = 0; ci < 4; ++ci)
#pragma unroll
    for (int nt = 0; nt < 4; ++nt)
      bfr[ci][nt] = bfrag_f32(snn_w2 + (nt*16 + m)*1024 + (w*4 + ci)*32 + q*8, 1.f);

  // layer-1 LIF state: lane's 32 A-fragment cells, packed as 16 f32 pairs.
  // spneg2 holds spikes as {-1.0f or -0.0f}: x + (-sp) is bit-identical to x - sp,
  // and removes the per-step re-compare (spike reused from last step's compare).
  f32x2_t c2[16], mem2[16], spneg2[16];
  f32x2_t beta2; beta2.x = 0.95f; beta2.y = 0.95f;
  {
    const int kb = w*128 + q*8;
#pragma unroll
    for (int ci = 0; ci < 4; ++ci) {
      const float* wp = snn_w1 + (kb + ci*32)*5;
      float wa[40];
#pragma unroll
      for (int u2 = 0; u2 < 10; ++u2) {
        const float4 t4 = *(const float4*)(wp + u2*4);
        wa[u2*4+0] = t4.x; wa[u2*4+1] = t4.y; wa[u2*4+2] = t4.z; wa[u2*4+3] = t4.w;
      }
      float cc[8];
#pragma unroll
      for (int j = 0; j < 8; ++j)
        cc[j] = f0*wa[j*5] + f1*wa[j*5+1] + f2*wa[j*5+2] + f3*wa[j*5+3] + f4*wa[j*5+4]
              + snn_b1[kb + ci*32 + j];
#pragma unroll
      for (int jj = 0; jj < 4; ++jj) {
        f32x2_t t; t.x = cc[2*jj]; t.y = cc[2*jj+1];
        c2[ci*4+jj] = t;
        f32x2_t z; z.x = 0.f; z.y = 0.f;
        mem2[ci*4+jj] = z;
        f32x2_t nz; nz.x = -0.0f; nz.y = -0.0f;
        spneg2[ci*4+jj] = nz;
      }
    }
  }

  BF8U afr[4];
  // mem = (0.95*mem + c) + (-sp)  [bit-exact np order: mul, add, add(-sp)]
  // afr word from spneg pair: perm picks hi16 of each (0xBF80 / 0x8000),
  // & 0x3F803F80 clears the sign -> packed bf16 {1.0, 0.0}. 2 instr/word vs 5.
  auto lif_update_pack = [&]() {
#pragma unroll
    for (int i = 0; i < 16; ++i) {
      const f32x2_t mk = pk_add(pk_add(pk_mul(mem2[i], beta2), c2[i]), spneg2[i]);
      mem2[i] = mk;
      f32x2_t sn;
      sn.x = mk.x > 1.f ? -1.0f : -0.0f;
      sn.y = mk.y > 1.f ? -1.0f : -0.0f;
      spneg2[i] = sn;
      afr[i>>2].u[i&3] =
          __builtin_amdgcn_perm(__float_as_uint(sn.y), __float_as_uint(sn.x), 0x07060302u)
          & 0x3F803F80u;
    }
  };
  lif_update_pack();                 // spikes(t=0) in registers

  // layer-2 LIF state, packed {rowA, rowB}; counts accumulated negative.
  f32x2_t m2;     m2.x = 0.f;     m2.y = 0.f;
  f32x2_t s2neg;  s2neg.x = -0.0f; s2neg.y = -0.0f;
  f32x2_t cntneg; cntneg.x = 0.f; cntneg.y = 0.f;
  f32x2_t sbias2; sbias2.x = b2l; sbias2.y = b2l;

  // paired-partials layout: [wave][row%8][col][row/8] f32.
  // write: 16x ds_write_b32 off one base (2-way bank alias = free);
  // read: rows (rA, rA+8) adjacent -> 8x ds_read_b64 lands {vA,vB} in pairs.
  const unsigned wbase = (unsigned)(w*4096 + (q&1)*2048 + (q>>1)*4 + m*8);
  const unsigned rbase = (unsigned)(rA*512 + rn*8);
  const f32x4_t z4 = {0.f, 0.f, 0.f, 0.f};

  auto lif2 = [&](f32x2_t cur2) {
    m2 = pk_add(pk_add(pk_mul(m2, beta2), cur2), s2neg);
    f32x2_t sn;
    sn.x = m2.x > 1.f ? -1.0f : -0.0f;
    sn.y = m2.y > 1.f ? -1.0f : -0.0f;
    s2neg = sn;
    cntneg = pk_add(cntneg, sn);
  };

  // one phase: reads(t-1) | MFMA(t)+writes | LIF(t+1) | reduce(t-1)
  auto phase = [&](unsigned cur, unsigned prv, bool doRead, bool doLif) {
    f32x2_t v2[8];
    if (doRead)
#pragma unroll
      for (int s = 0; s < 8; ++s)
        v2[s] = *(const f32x2_t*)(lds + prv + rbase + (unsigned)(s*4096));
    f32x4_t acc[4] = {z4, z4, z4, z4};
#pragma unroll
    for (int ci = 0; ci < 4; ++ci)
#pragma unroll
      for (int nt = 0; nt < 4; ++nt)
        acc[nt] = __builtin_amdgcn_mfma_f32_16x16x32_bf16(afr[ci].v, bfr[ci][nt], acc[nt], 0,0,0);
#pragma unroll
    for (int nt = 0; nt < 4; ++nt)
#pragma unroll
      for (int r = 0; r < 4; ++r)
        *(float*)(lds + cur + wbase + (unsigned)(r*512 + nt*128)) = acc[nt][r];
    if (doLif) lif_update_pack();
    if (doRead) {
      // exact same per-element tree shape: ((0+1)+(2+3))+((4+5)+(6+7)), then +bias
      const f32x2_t t = pk_add(pk_add(pk_add(v2[0],v2[1]), pk_add(v2[2],v2[3])),
                               pk_add(pk_add(v2[4],v2[5]), pk_add(v2[6],v2[7])));
      lif2(pk_add(t, sbias2));
    }
    __syncthreads();
  };

#pragma unroll 1
  for (int tt = 0; tt < NSTEPS; tt += 2) {
    phase(PB0, PB1, tt > 0, true);                 // t = tt   (even)
    phase(PB1, PB0, true,  tt + 1 < NSTEPS - 1);   // t = tt+1 (odd)
  }
  // partials(99) sit in PB1; reduced below, folded into the NN phase.

  // ============ NN branch + final SNN reduce (reads PB1, writes PB0) ============
#pragma unroll
  for (int ci = 0; ci < 4; ++ci)
#pragma unroll
    for (int nt = 0; nt < 4; ++nt)
      bfr[ci][nt] = bfrag_f32(nn_w2 + (nt*16 + m)*1024 + (w*4 + ci)*32 + q*8, 1.f);
  {
    // final SNN reduce (t = 99)
    f32x2_t v2[8];
#pragma unroll
    for (int s = 0; s < 8; ++s)
      v2[s] = *(const f32x2_t*)(lds + PB1 + rbase + (unsigned)(s*4096));
    const f32x2_t t = pk_add(pk_add(pk_add(v2[0],v2[1]), pk_add(v2[2],v2[3])),
                             pk_add(pk_add(v2[4],v2[5]), pk_add(v2[6],v2[7])));
    lif2(pk_add(t, sbias2));

    // NN hidden + MFMA
    BF8U hfr[4];
    const int kb = w*128 + q*8;
#pragma unroll
    for (int ci = 0; ci < 4; ++ci) {
      const float* wp = nn_w1 + (kb + ci*32)*5;
      float wa[40];
#pragma unroll
      for (int u2 = 0; u2 < 10; ++u2) {
        const float4 t4 = *(const float4*)(wp + u2*4);
        wa[u2*4+0] = t4.x; wa[u2*4+1] = t4.y; wa[u2*4+2] = t4.z; wa[u2*4+3] = t4.w;
      }
      float hv[8];
#pragma unroll
      for (int j = 0; j < 8; ++j) {
        const float h = f0*wa[j*5] + f1*wa[j*5+1] + f2*wa[j*5+2] + f3*wa[j*5+3] + f4*wa[j*5+4]
                      + nn_b1[kb + ci*32 + j];
        hv[j] = fmaxf(h, 0.f);
      }
#pragma unroll
      for (int jj = 0; jj < 4; ++jj) hfr[ci].u[jj] = pack2bf(hv[2*jj], hv[2*jj+1]);
    }
    f32x4_t acc[4] = {z4, z4, z4, z4};
#pragma unroll
    for (int ci = 0; ci < 4; ++ci)
#pragma unroll
      for (int nt = 0; nt < 4; ++nt)
        acc[nt] = __builtin_amdgcn_mfma_f32_16x16x32_bf16(hfr[ci].v, bfr[ci][nt], acc[nt], 0,0,0);
#pragma unroll
    for (int nt = 0; nt < 4; ++nt)
#pragma unroll
      for (int r = 0; r < 4; ++r)
        *(float*)(lds + PB0 + wbase + (unsigned)(r*512 + nt*128)) = acc[nt][r];
  }
  __syncthreads();
  {
    f32x2_t v2[8];
#pragma unroll
    for (int s = 0; s < 8; ++s)
      v2[s] = *(const f32x2_t*)(lds + PB0 + rbase + (unsigned)(s*4096));
    const f32x2_t t = pk_add(pk_add(pk_add(v2[0],v2[1]), pk_add(v2[2],v2[3])),
                             pk_add(pk_add(v2[4],v2[5]), pk_add(v2[6],v2[7])));
    const float nb = nn_b2[rn];
    f32x2_t nb2; nb2.x = nb; nb2.y = nb;
    const f32x2_t n2 = pk_add(t, nb2);
    // cnt = -cntneg (integer-valued): x * -0.0078125f is bit-identical to (-x)*0.0078125f
    comb_store(lds, rn,      rA,     cntneg.x * -0.0078125f);
    comb_store(lds, rn,      rA + 8, cntneg.y * -0.0078125f);
    comb_store(lds, 64 + rn, rA,     n2.x);
    comb_store(lds, 64 + rn, rA + 8, n2.y);
  }
  __syncthreads();

  // ======= CNN conv + relu + pairwise maxpool -> pooled bf16 frags [0,51200) =======
  {
    const int ch = tid >> 4;          // 0..31  (row = m)
    const float cw0 = conv_w[ch*3+0], cw1 = conv_w[ch*3+1], cw2 = conv_w[ch*3+2];
    const float cbb = conv_b[ch];
    const float* xw = xr + 5;
    float xm1 = 0.f, x0v = xw[0];
#pragma unroll 1
    for (int p = 0; p < 50; ++p) {
      const float xp1 = xw[2*p + 1];
      const float xp2 = (p < 49) ? xw[2*p + 2] : 0.f;
      const float av = cw0*xm1 + cw1*x0v + cw2*xp1 + cbb;
      const float bv = cw0*x0v + cw1*xp1 + cw2*xp2 + cbb;
      const float pv = fmaxf(fmaxf(av, 0.f), fmaxf(bv, 0.f));
      const int k = ch*50 + p;
      *(unsigned short*)(lds + (unsigned)((k>>5)*1024 + (((k>>3)&3)*16 + m)*16 + (k&7)*2)) = f2bfu(pv);
      xm1 = xp1; x0v = xp2;
    }
  }
  __syncthreads();

  // ================= CNN fc: wave w owns n-tiles {2w, 2w+1}, full K=1600 =================
  {
    const int c0 = (w*2 + 0)*16 + m;
    const int c1 = (w*2 + 1)*16 + m;
    f32x4_t e0 = z4, o0 = z4, e1 = z4, o1 = z4;
    if (use_bf) {
#pragma unroll 2
      for (int kc = 0; kc < 50; kc += 2) {
        const bf16x8_t a0 = *(const bf16x8_t*)(lds + (unsigned)((kc*64 + l)*16));
        const bf16x8_t a1 = *(const bf16x8_t*)(lds + (unsigned)(((kc+1)*64 + l)*16));
        e0 = __builtin_amdgcn_mfma_f32_16x16x32_bf16(a0, *(const bf16x8_t*)(fcwb + c0*1600 + kc*32 + q*8), e0, 0,0,0);
        o0 = __builtin_amdgcn_mfma_f32_16x16x32_bf16(a1, *(const bf16x8_t*)(fcwb + c0*1600 + (kc+1)*32 + q*8), o0, 0,0,0);
        e1 = __builtin_amdgcn_mfma_f32_16x16x32_bf16(a0, *(const bf16x8_t*)(fcwb + c1*1600 + kc*32 + q*8), e1, 0,0,0);
        o1 = __builtin_amdgcn_mfma_f32_16x16x32_bf16(a1, *(const bf16x8_t*)(fcwb + c1*1600 + (kc+1)*32 + q*8), o1, 0,0,0);
      }
    } else {
#pragma unroll 2
      for (int kc = 0; kc < 50; kc += 2) {
        const bf16x8_t a0 = *(const bf16x8_t*)(lds + (unsigned)((kc*64 + l)*16));
        const bf16x8_t a1 = *(const bf16x8_t*)(lds + (unsigned)(((kc+1)*64 + l)*16));
        e0 = __builtin_amdgcn_mfma_f32_16x16x32_bf16(a0, bfrag_f32(fc_w + c0*1600 + kc*32 + q*8, 1.f), e0, 0,0,0);
        o0 = __builtin_amdgcn_mfma_f32_16x16x32_bf16(a1, bfrag_f32(fc_w + c0*1600 + (kc+1)*32 + q*8, 1.f), o0, 0,0,0);
        e1 = __builtin_amdgcn_mfma_f32_16x16x32_bf16(a0, bfrag_f32(fc_w + c1*1600 + kc*32 + q*8, 1.f), e1, 0,0,0);
        o1 = __builtin_amdgcn_mfma_f32_16x16x32_bf16(a1, bfrag_f32(fc_w + c1*1600 + (kc+1)*32 + q*8, 1.f), o1, 0,0,0);
      }
    }
    const float fb0 = fc_b[c0], fb1 = fc_b[c1];
#pragma unroll
    for (int r = 0; r < 4; ++r) {
      comb_store(lds, 128 + c0, q*4 + r, (e0[r] + o0[r]) + fb0);
      comb_store(lds, 128 + c1, q*4 + r, (e1[r] + o1[r]) + fb1);
    }
  }
  __syncthreads();

  // ================= comb matmul: waves 0..3, wave w owns n-tile w, full K=384 =================
  if (w < 4) {
    const int cn = w*16 + m;
    f32x4_t oe = z4, oo = z4;
#pragma unroll
    for (int kc = 0; kc < 12; kc += 2) {
      const bf16x8_t a0 = *(const bf16x8_t*)(lds + COMBF + (unsigned)((kc*64 + l)*16));
      const bf16x8_t a1 = *(const bf16x8_t*)(lds + COMBF + (unsigned)(((kc+1)*64 + l)*16));
      const float s0 = (kc    < 2) ? 1.28f : 1.f;   // undo /128 on snn counts -> /100
      const float s1 = (kc+1 < 2) ? 1.28f : 1.f;
      oe = __builtin_amdgcn_mfma_f32_16x16x32_bf16(a0, bfrag_f32(comb_w + cn*384 + kc*32 + q*8, s0), oe, 0,0,0);
      oo = __builtin_amdgcn_mfma_f32_16x16x32_bf16(a1, bfrag_f32(comb_w + cn*384 + (kc+1)*32 + q*8, s1), oo, 0,0,0);
    }
    const float cb2 = comb_b[cn];
#pragma unroll
    for (int r = 0; r < 4; ++r)
      out[(row0 + q*4 + r)*64 + cn] = (oe[r] + oo[r]) + cb2;
  }
}

// fc_w fp32 -> bf16 (runs every call; d_ws is re-poisoned by the harness)
__global__ __launch_bounds__(256)
void fcw_to_bf16(const float* __restrict__ src, unsigned short* __restrict__ dst) {
  const int i = (blockIdx.x * 256 + threadIdx.x) * 4;
  const float4 v = *(const float4*)(src + i);
  ushort4 o;
  o.x = f2bfu(v.x); o.y = f2bfu(v.y); o.z = f2bfu(v.z); o.w = f2bfu(v.w);
  *(ushort4*)(dst + i) = o;
}

extern "C" void kernel_launch(void* const* d_in, const int* in_sizes, int n_in,
                              void* d_out, int out_size, void* d_ws, size_t ws_size,
                              hipStream_t stream) {
  const float* x       = (const float*)d_in[0];
  const float* snn_w1  = (const float*)d_in[1];
  const float* snn_b1  = (const float*)d_in[2];
  const float* snn_w2  = (const float*)d_in[3];
  const float* snn_b2  = (const float*)d_in[4];
  const float* nn_w1   = (const float*)d_in[5];
  const float* nn_b1   = (const float*)d_in[6];
  const float* nn_w2   = (const float*)d_in[7];
  const float* nn_b2   = (const float*)d_in[8];
  const float* conv_w  = (const float*)d_in[9];
  const float* conv_b  = (const float*)d_in[10];
  const float* fc_w    = (const float*)d_in[11];
  const float* fc_b    = (const float*)d_in[12];
  const float* comb_w  = (const float*)d_in[13];
  const float* comb_b  = (const float*)d_in[14];
  float* outp = (float*)d_out;

  const int rows = in_sizes[0] / 105;          // 16384
  const int grid = rows / 16;                  // 1024

  const size_t fcw_elems = (size_t)in_sizes[11];          // 256*1600 = 409600
  const int use_bf = (ws_size >= fcw_elems * 2) ? 1 : 0;
  unsigned short* fcwb = (unsigned short*)d_ws;
  if (use_bf) {
    fcw_to_bf16<<<dim3((unsigned)(fcw_elems / 1024)), dim3(256), 0, stream>>>(fc_w, fcwb);
  }

  hybrid_v13<<<dim3(grid), dim3(512), 0, stream>>>(
      x, snn_w1, snn_b1, snn_w2, snn_b2,
      nn_w1, nn_b1, nn_w2, nn_b2,
      conv_w, conv_b, fc_w, fc_b, comb_w, comb_b,
      fcwb, use_bf, outp);
}